// Round 13
// baseline (108.590 us; speedup 1.0000x reference)
//
#include <hip/hip_runtime.h>
#include <hip/hip_bf16.h>
#include <math.h>

// NT-Xent loss, N=4096, D=256, symmetric-GEMM version.
// loss = (1/2N) * sum_i [ 2 + log( sum_{j != i} exp(2*dot_ij - 2) ) - 2*dot(zn_i, zn_pair(i)) ]
//
// ROUND-13: r12's parallel-scratch epilogue won (103.99 -> 90.16). Profile now
// dominated by the harness's fixed 268MB workspace fill (43.5 us, untouchable).
// This round: (a) ticket finalize back in (passed r1/2/4/9/10/11), (b) 128-block
// k_normalize (r8-verified), (c) 512-thr / 8-wave k_simexp on the same 128x128
// tile: acc halves to 32 AGPR -> ~110 unified regs -> 4 waves/SIMD, 2x waves
// per barrier rendezvous (co-residency experiment; occupancy pinned ~5 waves/CU
// through all 13 rounds). Staging/swizzle math byte-identical per 8-row segment.
// K1: 128 blocks x 16 rows/wave: normalize -> bf16 zn; zero rowtotal/ticket/out.
// K2: 2080 upper-tri tiles, 8 waves 2x4 (wave = 64x32), XCD-bijective swizzle,
//     parallel-scratch epilogue, fence-free ticket finalize.

using short8  = __attribute__((ext_vector_type(8))) short;
using floatx4 = __attribute__((ext_vector_type(4))) float;

constexpr int TWO_N = 8192;
constexpr int DIM   = 256;
constexpr int NB    = 64;                 // 8192/128 tile blocks per side
constexpr int NTRI  = NB * (NB + 1) / 2;  // 2080
constexpr float INV2N = 1.0f / 8192.0f;

__device__ static inline unsigned short f2bf(float f) {
  unsigned u = __float_as_uint(f);
  return (unsigned short)((u + 0x7fffu + ((u >> 16) & 1u)) >> 16);  // RNE
}

__device__ static inline void async_copy16(const __hip_bfloat16* g, __hip_bfloat16* l) {
  __builtin_amdgcn_global_load_lds(
      (const __attribute__((address_space(1))) void*)(const void*)g,
      (__attribute__((address_space(3))) void*)(void*)l, 16, 0, 0);
}

// ---------------- K1: normalize + cast to bf16 (512 waves x 16 rows, r8-verified) ----------------
__global__ __launch_bounds__(256) void k_normalize(
    const float* __restrict__ zi, const float* __restrict__ zj,
    __hip_bfloat16* __restrict__ zn, float* __restrict__ rowtotal,
    float* __restrict__ out, unsigned* __restrict__ ticket)
{
  if (blockIdx.x == 0 && threadIdx.x == 0) { out[0] = 0.0f; ticket[0] = 0u; }
  if (blockIdx.x < 32) rowtotal[blockIdx.x * 256 + threadIdx.x] = 0.0f;

  const int lane = threadIdx.x & 63;
  const int wave = threadIdx.x >> 6;
  const int gw   = blockIdx.x * 4 + wave;   // 0..511 global wave id

  auto srcptr = [&](int it) -> const float* {
    return ((it < 8) ? zi : zj) + (size_t)(gw + (it & 7) * 512) * DIM;
  };

  float4 v = reinterpret_cast<const float4*>(srcptr(0))[lane];
#pragma unroll
  for (int it = 0; it < 16; ++it) {
    float4 vn;
    if (it < 15) vn = reinterpret_cast<const float4*>(srcptr(it + 1))[lane];
    float ss = v.x * v.x + v.y * v.y + v.z * v.z + v.w * v.w;
#pragma unroll
    for (int m = 32; m >= 1; m >>= 1) ss += __shfl_xor(ss, m, 64);
    float inv = 1.0f / fmaxf(sqrtf(ss), 1e-8f);
    ushort4 o;
    o.x = f2bf(v.x * inv); o.y = f2bf(v.y * inv);
    o.z = f2bf(v.z * inv); o.w = f2bf(v.w * inv);
    reinterpret_cast<ushort4*>(zn + (size_t)(gw + it * 512) * DIM)[lane] = o;
    v = vn;
  }
}

// ---------------- K2: 8-wave triangular GEMM + parallel-scratch epilogue + ticket ----------------
// 512 thr = 8 waves in 2x4: wm = wave>>2 (64-row half), wn = wave&3 (32-col quarter).
// Wave owns 64x32 = acc[4][2] of 16x16x32. LDS tiles [128][64] bf16, r0 swizzle
// (phys 16B slot = logical ^ (row&7)); staging waves 0-3 -> As quarters,
// 4-7 -> Bs quarters, 4 copies x 8 rows each.
__global__ __launch_bounds__(512) void k_simexp(
    const __hip_bfloat16* __restrict__ Z, float* __restrict__ rowtotal,
    float* __restrict__ out, unsigned* __restrict__ ticket)
{
  // 32 KB pool: As|Bs during K-loop, scratch[128][64] f32 after (exact overlay).
  __shared__ __align__(16) char smem[128 * 64 * 2 * 2];
  __shared__ float colsum[128];
  __shared__ float finsum[8];
  __shared__ int lastflag;
  __hip_bfloat16* As = (__hip_bfloat16*)smem;
  __hip_bfloat16* Bs = As + 128 * 64;
  float* scratch = (float*)smem;            // 128*64*4 = 32768 B

  const int tid  = threadIdx.x;
  const int lane = tid & 63;
  const int wave = tid >> 6;    // 0..7
  const int wm   = wave >> 2;   // 0..1: 64-row half
  const int wn   = wave & 3;    // 0..3: 32-col quarter

  // XCD-bijective chunked swizzle: 2080 = 8 * 260 (T1; FETCH -27% r10/r11)
  const int bid = blockIdx.x;
  const int u   = (bid & 7) * (NTRI / 8) + (bid >> 3);

  // triangular decode: u -> (ib <= jb)
  int jb = (int)((sqrtf(8.0f * (float)u + 1.0f) - 1.0f) * 0.5f);
  while ((jb + 1) * (jb + 2) / 2 <= u) ++jb;
  while (jb * (jb + 1) / 2 > u) --jb;
  const int ib = u - jb * (jb + 1) / 2;

  const bool diagblk = (ib == jb);
  const bool pairblk = (jb == ib + 32);
  const int i0 = ib * 128;
  const int j0 = jb * 128;

  if (tid < 128) colsum[tid] = 0.0f;

  floatx4 acc[4][2] = {};

  const int lane7 = lane & 7;
  const int sub   = lane >> 3;               // 0..7 subrow within 8-row segment
  const int gkoff = ((lane7 ^ sub) << 3);    // swizzled logical 16B slot to fetch
  const int q     = lane >> 4;               // 0..3
  const int c16   = lane & 15;

  // staging: waves 0-3 -> As quarter (wave&3)*32 rows, waves 4-7 -> Bs quarter
  const __hip_bfloat16* gbase =
      Z + (size_t)((wave < 4 ? i0 : j0) + (wave & 3) * 32) * DIM;
  __hip_bfloat16* lbase = ((wave < 4) ? As : Bs) + (wave & 3) * 32 * 64;

  for (int kk = 0; kk < 4; ++kk) {
    const int k0 = kk * 64;
#pragma unroll
    for (int c = 0; c < 4; ++c) {
      const __hip_bfloat16* gp = gbase + (size_t)(c * 8 + sub) * DIM + k0 + gkoff;
      async_copy16(gp, lbase + c * 512);   // + lane*16B implicit
    }
    __syncthreads();

#pragma unroll
    for (int ks = 0; ks < 2; ++ks) {
      const int phys = (ks * 4 + q) ^ lane7;  // physical 16B slot for this lane
      short8 a[4], b[2];
#pragma unroll
      for (int mt = 0; mt < 4; ++mt)
        a[mt] = *reinterpret_cast<const short8*>(
            As + (wm * 64 + mt * 16 + c16) * 64 + phys * 8);
#pragma unroll
      for (int nt = 0; nt < 2; ++nt)
        b[nt] = *reinterpret_cast<const short8*>(
            Bs + (wn * 32 + nt * 16 + c16) * 64 + phys * 8);
#pragma unroll
      for (int mt = 0; mt < 4; ++mt)
#pragma unroll
        for (int nt = 0; nt < 2; ++nt)
          acc[mt][nt] = __builtin_amdgcn_mfma_f32_16x16x32_bf16(
              a[mt], b[nt], acc[mt][nt], 0, 0, 0);
    }
    __syncthreads();
  }

  // ---- epilogue (parallel-scratch, 8-wave mapping) ----
  // C/D layout: col = lane&15 (within nt-tile), row = q*4 + reg (within mt-tile).
  // Block diagonal passes through waves with (wn>>1)==wm; there, with h=wn&1,
  // elem (r,r) sits at mt = 2h+nt, c16 == q*4+reg (each elem exactly once).
  const bool diagw = ((wn >> 1) == wm);
  const int  h     = wn & 1;
  float colacc[2] = {0.f, 0.f};
  float rowacc[4][4];
  float pc = 0.f;

#pragma unroll
  for (int mt = 0; mt < 4; ++mt) {
#pragma unroll
    for (int reg = 0; reg < 4; ++reg) {
      const bool onquad = (c16 == q * 4 + reg);
      const bool mdiag  = diagw && onquad && ((mt >> 1) == h);
      float s = 0.0f;
#pragma unroll
      for (int nt = 0; nt < 2; ++nt) {
        float e = __expf(2.0f * acc[mt][nt][reg] - 2.0f);
        bool skip = diagblk && mdiag && (nt == (mt & 1));  // true self-sim
        s += skip ? 0.0f : e;
        colacc[nt] += e;    // diag contamination ok: colsum unused for diagblk
      }
      if (pairblk && mdiag) pc += acc[mt][mt & 1][reg];    // pair dot
      rowacc[mt][reg] = s;
    }
  }

  if (!diagblk) {
#pragma unroll
    for (int nt = 0; nt < 2; ++nt) {
      float cs = colacc[nt];
      cs += __shfl_xor(cs, 16, 64);
      cs += __shfl_xor(cs, 32, 64);
      if (lane < 16) atomicAdd(&colsum[wn * 32 + nt * 16 + lane], cs);
    }
  }

  if (pairblk && diagw) {
#pragma unroll
    for (int m = 32; m >= 1; m >>= 1) pc += __shfl_xor(pc, m, 64);
    // each pair diag elem covers rows i and i+4096: loss += -2*(2*dot) per pair
    if (lane == 0) atomicAdd(out, -4.0f * pc * INV2N);
  }

  // row partials -> scratch[row][wn*16 + c16]; rotation-indexed reads below
#pragma unroll
  for (int mt = 0; mt < 4; ++mt)
#pragma unroll
    for (int reg = 0; reg < 4; ++reg)
      scratch[(wm * 64 + mt * 16 + q * 4 + reg) * 64 + wn * 16 + c16] =
          rowacc[mt][reg];

  __syncthreads();   // scratch writes + colsum atomics complete

  if (tid < 128) {
    float rs = 0.0f;
#pragma unroll
    for (int k = 0; k < 64; ++k)
      rs += scratch[tid * 64 + ((k + tid) & 63)];   // rotated: conflict-free
    atomicAdd(&rowtotal[i0 + tid], rs);
    if (!diagblk) atomicAdd(&rowtotal[j0 + tid], colsum[tid]);
  }

  // ---- fence-free ticket finalize (passed r1/2/4/9/10/11) ----
  __syncthreads();
  if (tid == 0) lastflag = (atomicAdd(ticket, 1u) == (unsigned)(NTRI - 1)) ? 1 : 0;
  __syncthreads();
  if (lastflag) {
    __threadfence();      // acquire side; ONE block only (cheap)
    float v = 0.0f;
#pragma unroll 4
    for (int r = tid; r < TWO_N; r += 512) {
      float tv = __hip_atomic_load(&rowtotal[r], __ATOMIC_RELAXED,
                                   __HIP_MEMORY_SCOPE_AGENT);
      v += 2.0f + __logf(tv);
    }
#pragma unroll
    for (int m = 32; m >= 1; m >>= 1) v += __shfl_xor(v, m, 64);
    if (lane == 0) finsum[wave] = v;
    __syncthreads();
    if (tid == 0) {
      float acc8 = 0.0f;
#pragma unroll
      for (int w = 0; w < 8; ++w) acc8 += finsum[w];
      atomicAdd(out, acc8 * INV2N);
    }
  }
}

// ---------------- launch ----------------
extern "C" void kernel_launch(void* const* d_in, const int* in_sizes, int n_in,
                              void* d_out, int out_size, void* d_ws, size_t ws_size,
                              hipStream_t stream) {
  const float* zi = (const float*)d_in[0];
  const float* zj = (const float*)d_in[1];
  float* out = (float*)d_out;

  __hip_bfloat16* zn = (__hip_bfloat16*)d_ws;                        // 8192*256*2 = 4 MB
  float* rowtotal = (float*)((char*)d_ws + (size_t)TWO_N * DIM * 2); // 8192*4 = 32 KB
  unsigned* ticket = (unsigned*)((char*)d_ws + (size_t)TWO_N * DIM * 2 + (size_t)TWO_N * 4);

  k_normalize<<<dim3(128), dim3(256), 0, stream>>>(zi, zj, zn, rowtotal, out, ticket);
  k_simexp<<<dim3(NTRI), dim3(512), 0, stream>>>(zn, rowtotal, out, ticket);
}

// Round 14
// 104.103 us; speedup vs baseline: 1.0431x; 1.0431x over previous
//
#include <hip/hip_runtime.h>
#include <hip/hip_bf16.h>
#include <math.h>

// NT-Xent loss, N=4096, D=256, symmetric-GEMM version.
// loss = (1/2N) * sum_i [ 2 + log( sum_{j != i} exp(2*dot_ij - 2) ) - 2*dot(zn_i, zn_pair(i)) ]
//
// ROUND-14: r13's 8-wave experiment REFUTED the occupancy theory (occupancy
// 16->47% yet k_simexp 35->56 us; per-wave fixed cost dominates). Revert to the
// r12 champion k_simexp (4 waves, padded [128][33] scratch epilogue = the r12
// win, 103.99 -> 90.16) and consolidate the two independently-proven overhead
// cuts: (a) fence-free ticket finalize fused into k_simexp (passed 7x:
// r1/2/4/9/10/11/13), (b) 128-block k_normalize (r8/r13-verified).
// K1: 128 blocks, 512 waves x 16 rows: normalize -> bf16 zn; zero rt/ticket/out.
// K2: 2080 upper-tri 128x128 tiles, 4 waves 2x2, r0 staging/swizzle/MFMA,
//     XCD-bijective swizzle, parallel-scratch epilogue, ticket finalize.

using short8  = __attribute__((ext_vector_type(8))) short;
using floatx4 = __attribute__((ext_vector_type(4))) float;

constexpr int TWO_N = 8192;
constexpr int DIM   = 256;
constexpr int NB    = 64;                 // 8192/128 tile blocks per side
constexpr int NTRI  = NB * (NB + 1) / 2;  // 2080
constexpr float INV2N = 1.0f / 8192.0f;

__device__ static inline unsigned short f2bf(float f) {
  unsigned u = __float_as_uint(f);
  return (unsigned short)((u + 0x7fffu + ((u >> 16) & 1u)) >> 16);  // RNE
}

__device__ static inline void async_copy16(const __hip_bfloat16* g, __hip_bfloat16* l) {
  __builtin_amdgcn_global_load_lds(
      (const __attribute__((address_space(1))) void*)(const void*)g,
      (__attribute__((address_space(3))) void*)(void*)l, 16, 0, 0);
}

// ---------------- K1: normalize + cast to bf16 (512 waves x 16 rows) ----------------
__global__ __launch_bounds__(256) void k_normalize(
    const float* __restrict__ zi, const float* __restrict__ zj,
    __hip_bfloat16* __restrict__ zn, float* __restrict__ rowtotal,
    float* __restrict__ out, unsigned* __restrict__ ticket)
{
  if (blockIdx.x == 0 && threadIdx.x == 0) { out[0] = 0.0f; ticket[0] = 0u; }
  if (blockIdx.x < 32) rowtotal[blockIdx.x * 256 + threadIdx.x] = 0.0f;

  const int lane = threadIdx.x & 63;
  const int wave = threadIdx.x >> 6;
  const int gw   = blockIdx.x * 4 + wave;   // 0..511 global wave id

  auto srcptr = [&](int it) -> const float* {
    return ((it < 8) ? zi : zj) + (size_t)(gw + (it & 7) * 512) * DIM;
  };

  float4 v = reinterpret_cast<const float4*>(srcptr(0))[lane];
#pragma unroll
  for (int it = 0; it < 16; ++it) {
    float4 vn;
    if (it < 15) vn = reinterpret_cast<const float4*>(srcptr(it + 1))[lane];
    float ss = v.x * v.x + v.y * v.y + v.z * v.z + v.w * v.w;
#pragma unroll
    for (int m = 32; m >= 1; m >>= 1) ss += __shfl_xor(ss, m, 64);
    float inv = 1.0f / fmaxf(sqrtf(ss), 1e-8f);
    ushort4 o;
    o.x = f2bf(v.x * inv); o.y = f2bf(v.y * inv);
    o.z = f2bf(v.z * inv); o.w = f2bf(v.w * inv);
    reinterpret_cast<ushort4*>(zn + (size_t)(gw + it * 512) * DIM)[lane] = o;
    v = vn;
  }
}

// ---------------- K2: triangular GEMM (r0) + parallel-scratch epilogue + ticket ----------------
// block 256 = 4 waves in 2x2; wave owns 64x64 (4x4 of 16x16x32 accumulators).
// LDS tiles [128][64] bf16 with 16B-slot XOR swizzle: phys_slot = logical ^ (row&7).
__global__ __launch_bounds__(256) void k_simexp(
    const __hip_bfloat16* __restrict__ Z, float* __restrict__ rowtotal,
    float* __restrict__ out, unsigned* __restrict__ ticket)
{
  // 32 KB shared pool: As|Bs during the K-loop, scratch[128][33] f32 after.
  __shared__ __align__(16) char smem[128 * 64 * 2 * 2];
  __shared__ float colsum[128];
  __shared__ float finsum[4];
  __shared__ int lastflag;
  __hip_bfloat16* As = (__hip_bfloat16*)smem;
  __hip_bfloat16* Bs = As + 128 * 64;
  float* scratch = (float*)smem;            // 128*33*4 = 16.9 KB <= 32 KB

  const int tid  = threadIdx.x;
  const int lane = tid & 63;
  const int wave = tid >> 6;
  const int wm   = wave >> 1;   // output row half
  const int wn   = wave & 1;    // output col half

  // XCD-bijective chunked swizzle: 2080 = 8 * 260 (T1; r10/r11 FETCH -27%)
  const int bid = blockIdx.x;
  const int u   = (bid & 7) * (NTRI / 8) + (bid >> 3);

  // triangular decode: u -> (ib <= jb)
  int jb = (int)((sqrtf(8.0f * (float)u + 1.0f) - 1.0f) * 0.5f);
  while ((jb + 1) * (jb + 2) / 2 <= u) ++jb;
  while (jb * (jb + 1) / 2 > u) --jb;
  const int ib = u - jb * (jb + 1) / 2;

  const bool diagblk = (ib == jb);
  const bool pairblk = (jb == ib + 32);
  const int i0 = ib * 128;
  const int j0 = jb * 128;

  if (tid < 128) colsum[tid] = 0.0f;

  floatx4 acc[4][4] = {};

  const int lane7 = lane & 7;
  const int sub   = lane >> 3;               // 0..7 subrow within 8-row segment
  const int gkoff = ((lane7 ^ sub) << 3);    // swizzled logical 16B slot to fetch
  const int q     = lane >> 4;               // 0..3
  const int c16   = lane & 15;

  // staging bases: waves 0,1 -> As (rows 0..63 / 64..127), waves 2,3 -> Bs
  const __hip_bfloat16* gbase =
      Z + (size_t)((wave < 2 ? i0 : j0) + (wave & 1) * 64) * DIM;
  __hip_bfloat16* lbase = ((wave < 2) ? As : Bs) + (wave & 1) * 64 * 64;

  for (int kk = 0; kk < 4; ++kk) {
    const int k0 = kk * 64;
#pragma unroll
    for (int c = 0; c < 8; ++c) {
      const __hip_bfloat16* gp = gbase + (size_t)(c * 8 + sub) * DIM + k0 + gkoff;
      async_copy16(gp, lbase + c * 512);   // + lane*16B implicit
    }
    __syncthreads();

#pragma unroll
    for (int ks = 0; ks < 2; ++ks) {
      const int phys = (ks * 4 + q) ^ lane7;  // physical 16B slot for this lane
      short8 a[4], b[4];
#pragma unroll
      for (int mt = 0; mt < 4; ++mt)
        a[mt] = *reinterpret_cast<const short8*>(
            As + (wm * 64 + mt * 16 + c16) * 64 + phys * 8);
#pragma unroll
      for (int nt = 0; nt < 4; ++nt)
        b[nt] = *reinterpret_cast<const short8*>(
            Bs + (wn * 64 + nt * 16 + c16) * 64 + phys * 8);
#pragma unroll
      for (int mt = 0; mt < 4; ++mt)
#pragma unroll
        for (int nt = 0; nt < 4; ++nt)
          acc[mt][nt] = __builtin_amdgcn_mfma_f32_16x16x32_bf16(
              a[mt], b[nt], acc[mt][nt], 0, 0, 0);
    }
    __syncthreads();
  }

  // ---- epilogue (parallel-scratch, r12-verified) ----
  // C/D layout: col = lane&15 (within nt-tile), row = q*4 + reg (within mt-tile).
  float colacc[4] = {0.f, 0.f, 0.f, 0.f};
  float rowacc[4][4];
  float pc = 0.f;
  const bool diagwave = (wm == wn);

#pragma unroll
  for (int mt = 0; mt < 4; ++mt) {
#pragma unroll
    for (int reg = 0; reg < 4; ++reg) {
      const bool onquad = (c16 == q * 4 + reg);  // lane holds a subtile-diag elem
      float s = 0.0f;
#pragma unroll
      for (int nt = 0; nt < 4; ++nt) {
        float e = __expf(2.0f * acc[mt][nt][reg] - 2.0f);
        bool skip = diagblk && diagwave && (nt == mt) && onquad;  // true self-sim
        s += skip ? 0.0f : e;
        colacc[nt] += e;    // diag contamination discarded (no colsum flush there)
      }
      if (pairblk && diagwave && onquad) pc += acc[mt][mt][reg];  // pair dot
      rowacc[mt][reg] = s;
    }
  }

  // column sums: reduce over the 4 q-groups (2 shfls), flush by lanes 0..15
  if (!diagblk) {
#pragma unroll
    for (int nt = 0; nt < 4; ++nt) {
      float cs = colacc[nt];
      cs += __shfl_xor(cs, 16, 64);
      cs += __shfl_xor(cs, 32, 64);
      if (lane < 16) atomicAdd(&colsum[wn * 64 + nt * 16 + lane], cs);
    }
  }

  if (pairblk && diagwave) {
#pragma unroll
    for (int m = 32; m >= 1; m >>= 1) pc += __shfl_xor(pc, m, 64);
    // each pair diag elem covers rows i and i+4096: loss += -2*(2*dot) per pair
    if (lane == 0) atomicAdd(out, -4.0f * pc * INV2N);
  }

  // row partials -> scratch[row][wn*16 + c16]  (pad 33 => conflict-free)
#pragma unroll
  for (int mt = 0; mt < 4; ++mt)
#pragma unroll
    for (int reg = 0; reg < 4; ++reg)
      scratch[(wm * 64 + mt * 16 + q * 4 + reg) * 33 + wn * 16 + c16] =
          rowacc[mt][reg];

  __syncthreads();   // scratch writes + colsum atomics complete

  if (tid < 128) {
    float rs = 0.0f;
#pragma unroll
    for (int k = 0; k < 32; ++k) rs += scratch[tid * 33 + k];
    atomicAdd(&rowtotal[i0 + tid], rs);
    if (!diagblk) atomicAdd(&rowtotal[j0 + tid], colsum[tid]);
  }

  // ---- fence-free ticket finalize (passed 7x: r1/2/4/9/10/11/13) ----
  __syncthreads();
  if (tid == 0) lastflag = (atomicAdd(ticket, 1u) == (unsigned)(NTRI - 1)) ? 1 : 0;
  __syncthreads();
  if (lastflag) {
    __threadfence();      // acquire side; ONE block only (cheap)
    float v = 0.0f;
#pragma unroll 4
    for (int r = tid; r < TWO_N; r += 256) {
      float tv = __hip_atomic_load(&rowtotal[r], __ATOMIC_RELAXED,
                                   __HIP_MEMORY_SCOPE_AGENT);
      v += 2.0f + __logf(tv);
    }
#pragma unroll
    for (int m = 32; m >= 1; m >>= 1) v += __shfl_xor(v, m, 64);
    if (lane == 0) finsum[wave] = v;
    __syncthreads();
    if (tid == 0)
      atomicAdd(out, (finsum[0] + finsum[1] + finsum[2] + finsum[3]) * INV2N);
  }
}

// ---------------- launch ----------------
extern "C" void kernel_launch(void* const* d_in, const int* in_sizes, int n_in,
                              void* d_out, int out_size, void* d_ws, size_t ws_size,
                              hipStream_t stream) {
  const float* zi = (const float*)d_in[0];
  const float* zj = (const float*)d_in[1];
  float* out = (float*)d_out;

  __hip_bfloat16* zn = (__hip_bfloat16*)d_ws;                        // 8192*256*2 = 4 MB
  float* rowtotal = (float*)((char*)d_ws + (size_t)TWO_N * DIM * 2); // 8192*4 = 32 KB
  unsigned* ticket = (unsigned*)((char*)d_ws + (size_t)TWO_N * DIM * 2 + (size_t)TWO_N * 4);

  k_normalize<<<dim3(128), dim3(256), 0, stream>>>(zi, zj, zn, rowtotal, out, ticket);
  k_simexp<<<dim3(NTRI), dim3(256), 0, stream>>>(zn, rowtotal, out, ticket);
}

// Round 15
// 88.172 us; speedup vs baseline: 1.2316x; 1.1807x over previous
//
#include <hip/hip_runtime.h>
#include <hip/hip_bf16.h>
#include <math.h>

// NT-Xent loss, N=4096, D=256, symmetric-GEMM version.
// loss = (1/2N) * sum_i [ 2 + log( sum_{j != i} exp(2*dot_ij - 2) ) - 2*dot(zn_i, zn_pair(i)) ]
//
// ROUND-15: r14 showed BOTH consolidations were regressions: the 128-block
// serial k_normalize costs ~10 us (16 dependent load->reduce->store rounds;
// the 2048-block version is ~2.5 us), and the fused ticket is the other r14
// delta vs the r12 champion. Revert to r12 EXACTLY (2048-blk norm, separate
// k_finalize, no ticket) + one free fix: rotate the scratch-write column by
// q*4 so the write bank (q*8+c16+const)%32 hits every bank exactly 2x (2-way
// = free, m136; was up to 4-way, 266K conflicts in r14). Read side sums all
// 32 row entries -> any within-row bijection is correctness-neutral.
// K1: 2048 blocks: normalize rows -> bf16 zn; zero rowtotal[8192] and out.
// K2: 2080 upper-tri 128x128 tiles, 4 waves 2x2, r0 staging/swizzle/MFMA,
//     XCD-bijective swizzle, parallel-scratch epilogue (r12 win).
// K3: 32 blocks: loss += sum_i (2 + log(rowtotal[i])) / 2N.

using short8  = __attribute__((ext_vector_type(8))) short;
using floatx4 = __attribute__((ext_vector_type(4))) float;

constexpr int TWO_N = 8192;
constexpr int DIM   = 256;
constexpr int NB    = 64;                 // 8192/128 tile blocks per side
constexpr int NTRI  = NB * (NB + 1) / 2;  // 2080
constexpr float INV2N = 1.0f / 8192.0f;

__device__ static inline unsigned short f2bf(float f) {
  unsigned u = __float_as_uint(f);
  return (unsigned short)((u + 0x7fffu + ((u >> 16) & 1u)) >> 16);  // RNE
}

__device__ static inline void async_copy16(const __hip_bfloat16* g, __hip_bfloat16* l) {
  __builtin_amdgcn_global_load_lds(
      (const __attribute__((address_space(1))) void*)(const void*)g,
      (__attribute__((address_space(3))) void*)(void*)l, 16, 0, 0);
}

// ---------------- K1: normalize + cast to bf16, zero accumulators ----------------
__global__ __launch_bounds__(256) void k_normalize(
    const float* __restrict__ zi, const float* __restrict__ zj,
    __hip_bfloat16* __restrict__ zn, float* __restrict__ rowtotal,
    float* __restrict__ out)
{
  if (blockIdx.x == 0 && threadIdx.x == 0) out[0] = 0.0f;
  if (blockIdx.x < 32) rowtotal[blockIdx.x * 256 + threadIdx.x] = 0.0f;

  const int lane = threadIdx.x & 63;
  const int wave = threadIdx.x >> 6;
  const int row  = blockIdx.x * 4 + wave;
  const float* src = (row < 4096) ? (zi + (size_t)row * DIM)
                                  : (zj + (size_t)(row - 4096) * DIM);
  float4 v = reinterpret_cast<const float4*>(src)[lane];
  float ss = v.x * v.x + v.y * v.y + v.z * v.z + v.w * v.w;
#pragma unroll
  for (int m = 32; m >= 1; m >>= 1) ss += __shfl_xor(ss, m, 64);
  float inv = 1.0f / fmaxf(sqrtf(ss), 1e-8f);
  ushort4 o;
  o.x = f2bf(v.x * inv); o.y = f2bf(v.y * inv);
  o.z = f2bf(v.z * inv); o.w = f2bf(v.w * inv);
  reinterpret_cast<ushort4*>(zn + (size_t)row * DIM)[lane] = o;
}

// ---------------- K2: triangular GEMM (r0) + parallel-scratch epilogue ----------------
// block 256 = 4 waves in 2x2; wave owns 64x64 (4x4 of 16x16x32 accumulators).
// LDS tiles [128][64] bf16 with 16B-slot XOR swizzle: phys_slot = logical ^ (row&7).
__global__ __launch_bounds__(256) void k_simexp(
    const __hip_bfloat16* __restrict__ Z, float* __restrict__ rowtotal,
    float* __restrict__ out)
{
  // 32 KB shared pool: As|Bs during the K-loop, scratch[128][33] f32 after.
  __shared__ __align__(16) char smem[128 * 64 * 2 * 2];
  __shared__ float colsum[128];
  __hip_bfloat16* As = (__hip_bfloat16*)smem;
  __hip_bfloat16* Bs = As + 128 * 64;
  float* scratch = (float*)smem;            // 128*33*4 = 16.9 KB <= 32 KB

  const int tid  = threadIdx.x;
  const int lane = tid & 63;
  const int wave = tid >> 6;
  const int wm   = wave >> 1;   // output row half
  const int wn   = wave & 1;    // output col half

  // XCD-bijective chunked swizzle: 2080 = 8 * 260 (T1; r10/r11 FETCH -27%)
  const int bid = blockIdx.x;
  const int u   = (bid & 7) * (NTRI / 8) + (bid >> 3);

  // triangular decode: u -> (ib <= jb)
  int jb = (int)((sqrtf(8.0f * (float)u + 1.0f) - 1.0f) * 0.5f);
  while ((jb + 1) * (jb + 2) / 2 <= u) ++jb;
  while (jb * (jb + 1) / 2 > u) --jb;
  const int ib = u - jb * (jb + 1) / 2;

  const bool diagblk = (ib == jb);
  const bool pairblk = (jb == ib + 32);
  const int i0 = ib * 128;
  const int j0 = jb * 128;

  if (tid < 128) colsum[tid] = 0.0f;

  floatx4 acc[4][4] = {};

  const int lane7 = lane & 7;
  const int sub   = lane >> 3;               // 0..7 subrow within 8-row segment
  const int gkoff = ((lane7 ^ sub) << 3);    // swizzled logical 16B slot to fetch
  const int q     = lane >> 4;               // 0..3
  const int c16   = lane & 15;

  // staging bases: waves 0,1 -> As (rows 0..63 / 64..127), waves 2,3 -> Bs
  const __hip_bfloat16* gbase =
      Z + (size_t)((wave < 2 ? i0 : j0) + (wave & 1) * 64) * DIM;
  __hip_bfloat16* lbase = ((wave < 2) ? As : Bs) + (wave & 1) * 64 * 64;

  for (int kk = 0; kk < 4; ++kk) {
    const int k0 = kk * 64;
#pragma unroll
    for (int c = 0; c < 8; ++c) {
      const __hip_bfloat16* gp = gbase + (size_t)(c * 8 + sub) * DIM + k0 + gkoff;
      async_copy16(gp, lbase + c * 512);   // + lane*16B implicit
    }
    __syncthreads();

#pragma unroll
    for (int ks = 0; ks < 2; ++ks) {
      const int phys = (ks * 4 + q) ^ lane7;  // physical 16B slot for this lane
      short8 a[4], b[4];
#pragma unroll
      for (int mt = 0; mt < 4; ++mt)
        a[mt] = *reinterpret_cast<const short8*>(
            As + (wm * 64 + mt * 16 + c16) * 64 + phys * 8);
#pragma unroll
      for (int nt = 0; nt < 4; ++nt)
        b[nt] = *reinterpret_cast<const short8*>(
            Bs + (wn * 64 + nt * 16 + c16) * 64 + phys * 8);
#pragma unroll
      for (int mt = 0; mt < 4; ++mt)
#pragma unroll
        for (int nt = 0; nt < 4; ++nt)
          acc[mt][nt] = __builtin_amdgcn_mfma_f32_16x16x32_bf16(
              a[mt], b[nt], acc[mt][nt], 0, 0, 0);
    }
    __syncthreads();
  }

  // ---- epilogue (parallel-scratch, r12-verified) ----
  // C/D layout: col = lane&15 (within nt-tile), row = q*4 + reg (within mt-tile).
  float colacc[4] = {0.f, 0.f, 0.f, 0.f};
  float rowacc[4][4];
  float pc = 0.f;
  const bool diagwave = (wm == wn);

#pragma unroll
  for (int mt = 0; mt < 4; ++mt) {
#pragma unroll
    for (int reg = 0; reg < 4; ++reg) {
      const bool onquad = (c16 == q * 4 + reg);  // lane holds a subtile-diag elem
      float s = 0.0f;
#pragma unroll
      for (int nt = 0; nt < 4; ++nt) {
        float e = __expf(2.0f * acc[mt][nt][reg] - 2.0f);
        bool skip = diagblk && diagwave && (nt == mt) && onquad;  // true self-sim
        s += skip ? 0.0f : e;
        colacc[nt] += e;    // diag contamination discarded (no colsum flush there)
      }
      if (pairblk && diagwave && onquad) pc += acc[mt][mt][reg];  // pair dot
      rowacc[mt][reg] = s;
    }
  }

  // column sums: reduce over the 4 q-groups (2 shfls), flush by lanes 0..15
  if (!diagblk) {
#pragma unroll
    for (int nt = 0; nt < 4; ++nt) {
      float cs = colacc[nt];
      cs += __shfl_xor(cs, 16, 64);
      cs += __shfl_xor(cs, 32, 64);
      if (lane < 16) atomicAdd(&colsum[wn * 64 + nt * 16 + lane], cs);
    }
  }

  if (pairblk && diagwave) {
#pragma unroll
    for (int m = 32; m >= 1; m >>= 1) pc += __shfl_xor(pc, m, 64);
    // each pair diag elem covers rows i and i+4096: loss += -2*(2*dot) per pair
    if (lane == 0) atomicAdd(out, -4.0f * pc * INV2N);
  }

  // row partials -> scratch[row][(wn*16+c16+q*4)&31]: q*4 rotation makes the
  // write bank (q*8+c16+const)%32 = every bank exactly 2x (2-way = free).
  // Reader sums all 32 entries of its row, so the rotation is sum-invariant.
#pragma unroll
  for (int mt = 0; mt < 4; ++mt)
#pragma unroll
    for (int reg = 0; reg < 4; ++reg)
      scratch[(wm * 64 + mt * 16 + q * 4 + reg) * 33 +
              ((wn * 16 + c16 + q * 4) & 31)] = rowacc[mt][reg];

  __syncthreads();   // scratch writes + colsum atomics complete

  if (tid < 128) {
    float rs = 0.0f;
#pragma unroll
    for (int k = 0; k < 32; ++k) rs += scratch[tid * 33 + k];
    atomicAdd(&rowtotal[i0 + tid], rs);
    if (!diagblk) atomicAdd(&rowtotal[j0 + tid], colsum[tid]);
  }
}

// ---------------- K3: finalize (logs + reduce) ----------------
__global__ __launch_bounds__(256) void k_finalize(
    const float* __restrict__ rowtotal, float* __restrict__ out)
{
  __shared__ float wsum[4];
  const int lane = threadIdx.x & 63;
  const int wave = threadIdx.x >> 6;
  const int row  = blockIdx.x * 256 + threadIdx.x;
  float v = 2.0f + __logf(rowtotal[row]);
#pragma unroll
  for (int m = 32; m >= 1; m >>= 1) v += __shfl_xor(v, m, 64);
  if (lane == 0) wsum[wave] = v;
  __syncthreads();
  if (threadIdx.x == 0)
    atomicAdd(out, (wsum[0] + wsum[1] + wsum[2] + wsum[3]) * INV2N);
}

// ---------------- launch ----------------
extern "C" void kernel_launch(void* const* d_in, const int* in_sizes, int n_in,
                              void* d_out, int out_size, void* d_ws, size_t ws_size,
                              hipStream_t stream) {
  const float* zi = (const float*)d_in[0];
  const float* zj = (const float*)d_in[1];
  float* out = (float*)d_out;

  __hip_bfloat16* zn = (__hip_bfloat16*)d_ws;                        // 8192*256*2 = 4 MB
  float* rowtotal = (float*)((char*)d_ws + (size_t)TWO_N * DIM * 2); // 8192*4 = 32 KB

  k_normalize<<<dim3(TWO_N / 4), dim3(256), 0, stream>>>(zi, zj, zn, rowtotal, out);
  k_simexp<<<dim3(NTRI), dim3(256), 0, stream>>>(zn, rowtotal, out);
  k_finalize<<<dim3(TWO_N / 256), dim3(256), 0, stream>>>(rowtotal, out);
}